// Round 4
// baseline (640.223 us; speedup 1.0000x reference)
//
#include <hip/hip_runtime.h>
#include <hip/hip_bf16.h>

typedef __bf16 bf16;
typedef __bf16 bf16x4 __attribute__((ext_vector_type(4)));
typedef __bf16 bf16x8 __attribute__((ext_vector_type(8)));
typedef float  f32x4  __attribute__((ext_vector_type(4)));

#define GAS __attribute__((address_space(1)))
#define LAS __attribute__((address_space(3)))

#define NROWS 4096
#define DIN   2048
#define DHID  8192
#define DOUT  2048

__device__ __forceinline__ void gload16(const void* g, void* l) {
    __builtin_amdgcn_global_load_lds((GAS void*)g, (LAS void*)l, 16, 0, 0);
}
template <int N> __device__ __forceinline__ void vmw() {
    asm volatile("s_waitcnt vmcnt(%0)" :: "n"(N) : "memory");
}
__device__ __forceinline__ void bsync() {
    asm volatile("" ::: "memory");
    __builtin_amdgcn_s_barrier();
    asm volatile("" ::: "memory");
}

// ---------------- Gram-Schmidt (MGS, matches reference) : 1 block, 1 wave ----
__global__ __launch_bounds__(64) void gs_kernel(const float* __restrict__ U,
                                                float* __restrict__ Vt) {
    __shared__ float Vs[8][DIN];
    const int l = threadIdx.x;
    float u[32];
    for (int r = 0; r < 8; ++r) {
        #pragma unroll
        for (int s = 0; s < 32; ++s) u[s] = U[(size_t)(l * 32 + s) * 8 + r];
        for (int j = 0; j < r; ++j) {
            float d = 0.f;
            #pragma unroll
            for (int s = 0; s < 32; ++s) d += Vs[j][l * 32 + s] * u[s];
            #pragma unroll
            for (int o = 32; o >= 1; o >>= 1) d += __shfl_xor(d, o);
            #pragma unroll
            for (int s = 0; s < 32; ++s) u[s] -= d * Vs[j][l * 32 + s];
        }
        float nr = 0.f;
        #pragma unroll
        for (int s = 0; s < 32; ++s) nr += u[s] * u[s];
        #pragma unroll
        for (int o = 32; o >= 1; o >>= 1) nr += __shfl_xor(nr, o);
        const float inv = 1.f / (sqrtf(nr) + 1e-6f);
        #pragma unroll
        for (int s = 0; s < 32; ++s) {
            float v = u[s] * inv;
            Vs[r][l * 32 + s] = v;
            Vt[r * DIN + l * 32 + s] = v;
        }
        __syncthreads();
    }
}

// ---------------- P = V^T @ W_random : 8 x 8192 (fp32) -----------------------
__global__ __launch_bounds__(256) void p_kernel(const float* __restrict__ W,
                                                const float* __restrict__ Vt,
                                                float* __restrict__ P) {
    const int t = threadIdx.x;
    const int c = blockIdx.x * 64 + (t & 63);
    const int part = t >> 6;
    float acc[8] = {};
    const int i0 = part * 512;
    #pragma unroll 4
    for (int i = i0; i < i0 + 512; ++i) {
        float w = W[(size_t)i * DHID + c];
        #pragma unroll
        for (int r = 0; r < 8; ++r) acc[r] = fmaf(Vt[r * DIN + i], w, acc[r]);
    }
    __shared__ float red[4][8][64];
    #pragma unroll
    for (int r = 0; r < 8; ++r) red[part][r][t & 63] = acc[r];
    __syncthreads();
    for (int idx = t; idx < 512; idx += 256) {
        int r = idx >> 6, cc = idx & 63;
        P[(size_t)r * DHID + blockIdx.x * 64 + cc] =
            red[0][r][cc] + red[1][r][cc] + red[2][r][cc] + red[3][r][cc];
    }
}

// ------- xV = x @ V (4096x8) fused with fp32->bf16 cast of x -----------------
// 256 thr = 4 waves, one row per wave. float4 loads; writes xV row + xb row.
__global__ __launch_bounds__(256) void xv_kernel(const float* __restrict__ x,
                                                 const float* __restrict__ Vt,
                                                 float* __restrict__ xV,
                                                 bf16* __restrict__ xb) {
    const int row = blockIdx.x * 4 + (threadIdx.x >> 6);
    const int l = threadIdx.x & 63;
    const float* xr = x + (size_t)row * DIN;
    bf16* xbr = xb + (size_t)row * DIN;
    float acc[8] = {};
    #pragma unroll
    for (int s = 0; s < 8; ++s) {
        const int c0 = (s * 64 + l) * 4;
        float4 v = *(const float4*)&xr[c0];
        bf16x4 o = { (bf16)v.x, (bf16)v.y, (bf16)v.z, (bf16)v.w };
        *(bf16x4*)&xbr[c0] = o;
        #pragma unroll
        for (int r = 0; r < 8; ++r) {
            float4 vt = *(const float4*)&Vt[r * DIN + c0];
            acc[r] = fmaf(v.x, vt.x, fmaf(v.y, vt.y, fmaf(v.z, vt.z, fmaf(v.w, vt.w, acc[r]))));
        }
    }
    #pragma unroll
    for (int r = 0; r < 8; ++r) {
        float d = acc[r];
        #pragma unroll
        for (int o = 32; o >= 1; o >>= 1) d += __shfl_xor(d, o);
        if (l == 0) xV[(size_t)row * 8 + r] = d;
    }
}

// ---------------- transpose + fp32->bf16 : in RxC fp32 -> out CxR bf16 -------
__global__ __launch_bounds__(256) void tconv_kernel(const float* __restrict__ in,
                                                    bf16* __restrict__ out,
                                                    int R, int C) {
    __shared__ bf16 tile[64][66];
    const int t = threadIdx.x;
    const int n0 = blockIdx.x * 64, k0 = blockIdx.y * 64;
    const int rr = t >> 4, c4 = (t & 15) * 4;
    #pragma unroll
    for (int q = 0; q < 4; ++q) {
        int row = k0 + rr + q * 16;
        float4 v = *(const float4*)&in[(size_t)row * C + n0 + c4];
        tile[c4 + 0][rr + q * 16] = (bf16)v.x;
        tile[c4 + 1][rr + q * 16] = (bf16)v.y;
        tile[c4 + 2][rr + q * 16] = (bf16)v.z;
        tile[c4 + 3][rr + q * 16] = (bf16)v.w;
    }
    __syncthreads();
    const int n = t >> 2, kk = (t & 3) * 16;
    unsigned int w[8];
    #pragma unroll
    for (int i = 0; i < 8; ++i) w[i] = *(const unsigned int*)&tile[n][kk + i * 2];
    uint4 lo = { w[0], w[1], w[2], w[3] }, hi = { w[4], w[5], w[6], w[7] };
    uint4* dst = (uint4*)&out[(size_t)(n0 + n) * R + k0 + kk];
    dst[0] = lo;
    dst[1] = hi;
}

// -------- reduce: out += p1 + bias (fp32, float4) ----------------------------
__global__ __launch_bounds__(256) void redk(float* __restrict__ out,
                                            const float* __restrict__ p1,
                                            const float* __restrict__ bias) {
    const size_t i = (size_t)blockIdx.x * 256 + threadIdx.x;
    float4 a = ((const float4*)out)[i];
    float4 b = ((const float4*)p1)[i];
    const int c4 = (int)(i & (DOUT / 4 - 1)) * 4;
    float4 bb = *(const float4*)&bias[c4];
    float4 r = { a.x + b.x + bb.x, a.y + b.y + bb.y,
                 a.z + b.z + bb.z, a.w + b.w + bb.w };
    ((float4*)out)[i] = r;
}

// ---------------- bf16 GEMM, BK=32, ring-4, phase-split compute --------------
// Per K-tile, 2 phases: {ds_read subtile + stage half of (kt+3) -> barrier ->
// setprio + 16 MFMA -> barrier}. The NEXT tile's vmcnt wait is placed at the
// END of the tile, immediately before the closing barrier — so the barrier
// certifies every wave's loads have landed before anyone ds_reads (the round-3
// NaN was vmw-after-barrier: wave X read rows wave Y hadn't finished staging).
// Zero-conflict XOR swizzle (16B granular, inverse-swizzled global source).
// EPI==1: rank-8 correction + exact GELU, bf16 out. EPI==2: split-K fp32
//         partial (sk=bid&1: sk0 -> Cout, sk1 -> e1).
template <int BM, int BN, int WM, int WN, int CR, int CC, int EPI>
__global__ __launch_bounds__(512) void gemm8p(const bf16* __restrict__ A,
                                              const bf16* __restrict__ Bt,
                                              const int N, const int nk, const int lda,
                                              const float* __restrict__ e0,
                                              const float* __restrict__ e1,
                                              void* __restrict__ Cout) {
    constexpr int MF = BM / (WM * 16);
    constexpr int NF = BN / (WN * 16);
    constexpr int ABYTES = BM * 64;
    constexpr int BUFB = (BM + BN) * 64;
    constexpr int LA = BM / 128, LB = BN / 128, LPT = LA + LB;
    __shared__ __align__(128) char lds[4 * BUFB];

    const int t = threadIdx.x;
    const int wid = t >> 6, lane = t & 63;
    const int wr = wid / WN, wc = wid % WN;
    const int lrow = lane & 15;
    const int lk2 = (lane >> 4) * 16;

    int bid = blockIdx.x, sk = 0;
    if constexpr (EPI == 2) { sk = bid & 1; bid >>= 1; }
    const int chunks_c = (N / BN) / CC;
    const int xc = bid & 7;
    const int ii = bid >> 3;
    const int bm = (xc / chunks_c) * CR + ii / CC;
    const int bn = (xc % chunks_c) * CC + ii % CC;

    const size_t koff = (size_t)sk * nk * 32;
    const bf16* Abase = A + (size_t)bm * BM * lda + koff;
    const bf16* Bbase = Bt + (size_t)bn * BN * lda + koff;

    const int ar0 = wr * (MF * 16) + lrow;
    const unsigned aoff = (unsigned)(ar0 * 64 + lk2) ^ (unsigned)(((ar0 >> 1) & 3) << 4);
    const int br0 = wc * (NF * 16) + lrow;
    const unsigned boff = (unsigned)ABYTES +
        ((unsigned)(br0 * 64 + lk2) ^ (unsigned)(((br0 >> 1) & 3) << 4));

    f32x4 acc[MF][NF] = {};

    auto STAGE = [&](int kt, int part) {
        const size_t ko = (size_t)kt * 32;
        char* dstb = lds + (kt & 3) * BUFB;
        if (part == 0) {
            #pragma unroll
            for (int i2 = 0; i2 < LA; ++i2) {
                const int lin = i2 * 512 + t;
                const int row = lin >> 2;
                const int c16 = (lin & 3) ^ ((lin >> 3) & 3);
                gload16(Abase + (size_t)row * lda + ko + c16 * 8,
                        dstb + (i2 * 512 + (t & 448)) * 16);
            }
        } else {
            #pragma unroll
            for (int i2 = 0; i2 < LB; ++i2) {
                const int lin = i2 * 512 + t;
                const int row = lin >> 2;
                const int c16 = (lin & 3) ^ ((lin >> 3) & 3);
                gload16(Bbase + (size_t)row * lda + ko + c16 * 8,
                        dstb + ABYTES + (i2 * 512 + (t & 448)) * 16);
            }
        }
    };

    // TILE body WITHOUT the closing vmw+bsync (caller appends them).
    auto TILE = [&](int kt, bool dostage) {
        const char* bp = lds + (kt & 3) * BUFB;
        bf16x8 av0[MF / 2], av1[MF / 2], bv[NF];
        // ---- phase 0: read half-A + all-B, stage A of kt+3, 16 MFMA ----
        #pragma unroll
        for (int m = 0; m < MF / 2; ++m)
            av0[m] = *(const bf16x8*)(bp + aoff + m * 1024);
        #pragma unroll
        for (int n = 0; n < NF; ++n)
            bv[n] = *(const bf16x8*)(bp + boff + n * 1024);
        if (dostage) STAGE(kt + 3, 0);
        __builtin_amdgcn_sched_barrier(0);
        bsync();
        __builtin_amdgcn_s_setprio(1);
        #pragma unroll
        for (int m = 0; m < MF / 2; ++m)
            #pragma unroll
            for (int n = 0; n < NF; ++n)
                acc[m][n] = __builtin_amdgcn_mfma_f32_16x16x32_bf16(av0[m], bv[n], acc[m][n], 0, 0, 0);
        __builtin_amdgcn_s_setprio(0);
        bsync();
        // ---- phase 1: read other half-A, stage B of kt+3, 16 MFMA ----
        #pragma unroll
        for (int m = 0; m < MF / 2; ++m)
            av1[m] = *(const bf16x8*)(bp + aoff + (m + MF / 2) * 1024);
        if (dostage) STAGE(kt + 3, 1);
        __builtin_amdgcn_sched_barrier(0);
        bsync();
        __builtin_amdgcn_s_setprio(1);
        #pragma unroll
        for (int m = 0; m < MF / 2; ++m)
            #pragma unroll
            for (int n = 0; n < NF; ++n)
                acc[m + MF / 2][n] = __builtin_amdgcn_mfma_f32_16x16x32_bf16(av1[m], bv[n], acc[m + MF / 2][n], 0, 0, 0);
        __builtin_amdgcn_s_setprio(0);
    };

    #pragma unroll
    for (int p = 0; p < 3; ++p) { STAGE(p, 0); STAGE(p, 1); }
    vmw<2 * LPT>(); bsync();                       // tile 0 landed, all waves
    int kt = 0;
    for (; kt < nk - 3; ++kt) {
        TILE(kt, true);
        vmw<2 * LPT>();                            // tile kt+1 landed...
        bsync();                                   // ...for EVERY wave
    }
    TILE(kt, false); vmw<LPT>(); bsync(); ++kt;    // kt = nk-3
    TILE(kt, false); vmw<0>();   bsync(); ++kt;    // kt = nk-2
    TILE(kt, false); bsync();                      // kt = nk-1

    const int jrow = (lane >> 4) << 2;
    if constexpr (EPI == 1) {
        float* xVl = (float*)lds;                 // BM x 8
        float* Pl  = (float*)(lds + BM * 32);     // 8 x BN
        for (int idx = t; idx < BM * 8; idx += 512)
            xVl[idx] = e0[((size_t)bm * BM + (idx >> 3)) * 8 + (idx & 7)];
        for (int idx = t; idx < BN * 8; idx += 512)
            Pl[idx] = e1[(size_t)(idx / BN) * N + (size_t)bn * BN + (idx % BN)];
        bsync();
        bf16* outp = (bf16*)Cout;
        #pragma unroll
        for (int m = 0; m < MF; ++m)
            #pragma unroll
            for (int n = 0; n < NF; ++n)
                #pragma unroll
                for (int j = 0; j < 4; ++j) {
                    const int rl = wr * (MF * 16) + m * 16 + jrow + j;
                    const int cl = wc * (NF * 16) + n * 16 + lrow;
                    float v = acc[m][n][j];
                    float corr = 0.f;
                    #pragma unroll
                    for (int r = 0; r < 8; ++r)
                        corr = fmaf(xVl[rl * 8 + r], Pl[r * BN + cl], corr);
                    v = fmaf(-2.f, corr, v);
                    v = 0.5f * v * (1.f + erff(v * 0.70710678118654752440f));
                    outp[((size_t)bm * BM + rl) * N + bn * BN + cl] = (bf16)v;
                }
    } else {
        float* outp = sk ? const_cast<float*>(e1) : (float*)Cout;
        #pragma unroll
        for (int m = 0; m < MF; ++m)
            #pragma unroll
            for (int n = 0; n < NF; ++n)
                #pragma unroll
                for (int j = 0; j < 4; ++j) {
                    const int rl = wr * (MF * 16) + m * 16 + jrow + j;
                    const int cl = wc * (NF * 16) + n * 16 + lrow;
                    outp[((size_t)bm * BM + rl) * N + bn * BN + cl] = acc[m][n][j];
                }
    }
}

extern "C" void kernel_launch(void* const* d_in, const int* in_sizes, int n_in,
                              void* d_out, int out_size, void* d_ws, size_t ws_size,
                              hipStream_t stream) {
    const float* x     = (const float*)d_in[0];
    const float* hra_u = (const float*)d_in[1];
    const float* Wr    = (const float*)d_in[2];
    const float* Wo    = (const float*)d_in[3];
    const float* bias  = (const float*)d_in[4];
    float* out = (float*)d_out;
    char* ws = (char*)d_ws;

    float* Vt  = (float*)(ws + 0);          //  64 KB : 8 x 2048
    float* P   = (float*)(ws + 65536);      // 256 KB : 8 x 8192
    float* xV  = (float*)(ws + 327680);     // 128 KB : 4096 x 8
    bf16*  xb  = (bf16*)(ws + 458752);      //  16 MB : 4096 x 2048
    bf16*  WrT = (bf16*)(ws + 17235968);    //  32 MB : 8192 x 2048
    bf16*  WoT = (bf16*)(ws + 50790400);    //  32 MB : 2048 x 8192
    bf16*  hb  = (bf16*)(ws + 84344832);    //  64 MB : 4096 x 8192
    // split-K partial for sk=1: 32 MB over xb+WrT head (both dead after GEMM1)
    float* p1  = (float*)(ws + 458752);

    gs_kernel<<<dim3(1), dim3(64), 0, stream>>>(hra_u, Vt);
    p_kernel<<<dim3(DHID / 64), dim3(256), 0, stream>>>(Wr, Vt, P);
    xv_kernel<<<dim3(NROWS / 4), dim3(256), 0, stream>>>(x, Vt, xV, xb);
    tconv_kernel<<<dim3(DHID / 64, DIN / 64), dim3(256), 0, stream>>>(Wr, WrT, DIN, DHID);
    tconv_kernel<<<dim3(DOUT / 64, DHID / 64), dim3(256), 0, stream>>>(Wo, WoT, DHID, DOUT);

    // GEMM1: 4096x8192 k=2048, 512 blocks (16x32 tiles), XCD chunk 8x8
    gemm8p<256, 256, 2, 4, 8, 8, 1><<<dim3(512), dim3(512), 0, stream>>>(
        xb, WrT, DHID, DIN / 32, DIN, xV, P, (void*)hb);
    // GEMM2: 4096x2048 k=8192, split-K=2: 256 blocks (16x8 tiles x 2), chunk 4x4
    gemm8p<256, 256, 2, 4, 4, 4, 2><<<dim3(256), dim3(512), 0, stream>>>(
        hb, WoT, DOUT, DHID / 64, DHID, nullptr, p1, (void*)out);
    redk<<<dim3((NROWS * DOUT) / 1024), dim3(256), 0, stream>>>(out, p1, bias);
}

// Round 9
// 573.105 us; speedup vs baseline: 1.1171x; 1.1171x over previous
//
#include <hip/hip_runtime.h>
#include <hip/hip_bf16.h>

typedef __bf16 bf16;
typedef __bf16 bf16x4 __attribute__((ext_vector_type(4)));
typedef __bf16 bf16x8 __attribute__((ext_vector_type(8)));
typedef float  f32x4  __attribute__((ext_vector_type(4)));

#define GAS __attribute__((address_space(1)))
#define LAS __attribute__((address_space(3)))

#define NROWS 4096
#define DIN   2048
#define DHID  8192
#define DOUT  2048

__device__ __forceinline__ void gload16(const void* g, void* l) {
    __builtin_amdgcn_global_load_lds((GAS void*)g, (LAS void*)l, 16, 0, 0);
}
template <int N> __device__ __forceinline__ void vmw() {
    asm volatile("s_waitcnt vmcnt(%0)" :: "n"(N));
}
__device__ __forceinline__ void SB() { __builtin_amdgcn_sched_barrier(0); }

// ---------------- Gram-Schmidt (MGS, matches reference) : 1 block, 1 wave ----
__global__ __launch_bounds__(64) void gs_kernel(const float* __restrict__ U,
                                                float* __restrict__ Vt) {
    __shared__ float Vs[8][DIN];
    const int l = threadIdx.x;
    float u[32];
    for (int r = 0; r < 8; ++r) {
        #pragma unroll
        for (int s = 0; s < 32; ++s) u[s] = U[(size_t)(l * 32 + s) * 8 + r];
        for (int j = 0; j < r; ++j) {
            float d = 0.f;
            #pragma unroll
            for (int s = 0; s < 32; ++s) d += Vs[j][l * 32 + s] * u[s];
            #pragma unroll
            for (int o = 32; o >= 1; o >>= 1) d += __shfl_xor(d, o);
            #pragma unroll
            for (int s = 0; s < 32; ++s) u[s] -= d * Vs[j][l * 32 + s];
        }
        float nr = 0.f;
        #pragma unroll
        for (int s = 0; s < 32; ++s) nr += u[s] * u[s];
        #pragma unroll
        for (int o = 32; o >= 1; o >>= 1) nr += __shfl_xor(nr, o);
        const float inv = 1.f / (sqrtf(nr) + 1e-6f);
        #pragma unroll
        for (int s = 0; s < 32; ++s) {
            float v = u[s] * inv;
            Vs[r][l * 32 + s] = v;
            Vt[r * DIN + l * 32 + s] = v;
        }
        __syncthreads();
    }
}

// ---------------- P = V^T @ W_random : 8 x 8192 (fp32), 256 blocks -----------
__global__ __launch_bounds__(256) void p_kernel(const float* __restrict__ W,
                                                const float* __restrict__ Vt,
                                                float* __restrict__ P) {
    const int t = threadIdx.x;
    const int c = blockIdx.x * 32 + (t & 31);
    const int part = t >> 5;                       // 8 parts x 256 rows
    float acc[8] = {};
    const int i0 = part * 256;
    #pragma unroll 4
    for (int i = i0; i < i0 + 256; ++i) {
        float w = W[(size_t)i * DHID + c];
        #pragma unroll
        for (int r = 0; r < 8; ++r) acc[r] = fmaf(Vt[r * DIN + i], w, acc[r]);
    }
    __shared__ float red[8][8][32];
    #pragma unroll
    for (int r = 0; r < 8; ++r) red[part][r][t & 31] = acc[r];
    __syncthreads();
    {
        int r = t >> 5, cc = t & 31;
        float s = 0.f;
        #pragma unroll
        for (int p = 0; p < 8; ++p) s += red[p][r][cc];
        P[(size_t)r * DHID + blockIdx.x * 32 + cc] = s;
    }
}

// ------- xV = x @ V (4096x8) fused with fp32->bf16 cast of x -----------------
__global__ __launch_bounds__(256) void xv_kernel(const float* __restrict__ x,
                                                 const float* __restrict__ Vt,
                                                 float* __restrict__ xV,
                                                 bf16* __restrict__ xb) {
    const int row = blockIdx.x * 4 + (threadIdx.x >> 6);
    const int l = threadIdx.x & 63;
    const float* xr = x + (size_t)row * DIN;
    bf16* xbr = xb + (size_t)row * DIN;
    float acc[8] = {};
    #pragma unroll
    for (int s = 0; s < 8; ++s) {
        const int c0 = (s * 64 + l) * 4;
        float4 v = *(const float4*)&xr[c0];
        bf16x4 o = { (bf16)v.x, (bf16)v.y, (bf16)v.z, (bf16)v.w };
        *(bf16x4*)&xbr[c0] = o;
        #pragma unroll
        for (int r = 0; r < 8; ++r) {
            float4 vt = *(const float4*)&Vt[r * DIN + c0];
            acc[r] = fmaf(v.x, vt.x, fmaf(v.y, vt.y, fmaf(v.z, vt.z, fmaf(v.w, vt.w, acc[r]))));
        }
    }
    #pragma unroll
    for (int r = 0; r < 8; ++r) {
        float d = acc[r];
        #pragma unroll
        for (int o = 32; o >= 1; o >>= 1) d += __shfl_xor(d, o);
        if (l == 0) xV[(size_t)row * 8 + r] = d;
    }
}

// ---------------- transpose + fp32->bf16 : in RxC fp32 -> out CxR bf16 -------
__global__ __launch_bounds__(256) void tconv_kernel(const float* __restrict__ in,
                                                    bf16* __restrict__ out,
                                                    int R, int C) {
    __shared__ bf16 tile[64][66];
    const int t = threadIdx.x;
    const int n0 = blockIdx.x * 64, k0 = blockIdx.y * 64;
    const int rr = t >> 4, c4 = (t & 15) * 4;
    #pragma unroll
    for (int q = 0; q < 4; ++q) {
        int row = k0 + rr + q * 16;
        float4 v = *(const float4*)&in[(size_t)row * C + n0 + c4];
        tile[c4 + 0][rr + q * 16] = (bf16)v.x;
        tile[c4 + 1][rr + q * 16] = (bf16)v.y;
        tile[c4 + 2][rr + q * 16] = (bf16)v.z;
        tile[c4 + 3][rr + q * 16] = (bf16)v.w;
    }
    __syncthreads();
    const int n = t >> 2, kk = (t & 3) * 16;
    unsigned int w[8];
    #pragma unroll
    for (int i = 0; i < 8; ++i) w[i] = *(const unsigned int*)&tile[n][kk + i * 2];
    uint4 lo = { w[0], w[1], w[2], w[3] }, hi = { w[4], w[5], w[6], w[7] };
    uint4* dst = (uint4*)&out[(size_t)(n0 + n) * R + k0 + kk];
    dst[0] = lo;
    dst[1] = hi;
}

// -------- reduce: out += p1 + bias (fp32, float4) ----------------------------
__global__ __launch_bounds__(256) void redk(float* __restrict__ out,
                                            const float* __restrict__ p1,
                                            const float* __restrict__ bias) {
    const size_t i = (size_t)blockIdx.x * 256 + threadIdx.x;
    float4 a = ((const float4*)out)[i];
    float4 b = ((const float4*)p1)[i];
    const int c4 = (int)(i & (DOUT / 4 - 1)) * 4;
    float4 bb = *(const float4*)&bias[c4];
    float4 r = { a.x + b.x + bb.x, a.y + b.y + bb.y,
                 a.z + b.z + bb.z, a.w + b.w + bb.w };
    ((float4*)out)[i] = r;
}

// ------- bf16 GEMM, 256x256 tile, BK=64, dbuf-2, 4-phase m201 schedule -------
// 512 thr = 8 waves (2M x 4N), per-wave 128x64. Per K-tile (BK=64), 4 phases:
//   ph1: ds_read av(k0,m0-3)+bv(k0)      | stage Ak0(kt+1) | sync | 16 MFMA
//   ph2: ds_read av(k0,m4-7)             | stage Bk0(kt+1) | vmcnt(4) sync | 16 MFMA
//   ph3: ds_read av(k1,m0-3)+bv(k1)      | stage Ak1(kt+1) | sync | 16 MFMA
//   ph4: ds_read av(k1,m4-7)             | stage Bk1(kt+1) | vmcnt(4) sync | 16 MFMA
// sync = sched_barrier(0); BARE s_barrier; asm lgkmcnt(0); sched_barrier(0)
// (no asm-memory wrappers — suspected to force full vmcnt/lgkmcnt drains).
// vmcnt(4) BEFORE its barrier: barrier certifies quarters landed for all waves.
// LDS: 2 buffers x 64KB = [Ak0|Ak1|Bk0|Bk1] x 16KB, XOR-swizzled 64B rows.
// EPI==1: rank-8 correction + exact GELU, bf16 out. EPI==2: split-K fp32
//         partial (sk=bid&1: sk0 -> Cout, sk1 -> e1).
template <int CR, int CC, int EPI>
__global__ __launch_bounds__(512) void gemm4p(const bf16* __restrict__ A,
                                              const bf16* __restrict__ Bt,
                                              const int N, const int nk, const int lda,
                                              const float* __restrict__ e0,
                                              const float* __restrict__ e1,
                                              void* __restrict__ Cout) {
    __shared__ __align__(128) char lds[131072];
    const int t = threadIdx.x;
    const int wid = t >> 6, lane = t & 63;
    const int wr = wid >> 2, wc = wid & 3;          // 2M x 4N
    const int lrow = lane & 15;
    const int lk2 = (lane >> 4) * 16;

    int bid = blockIdx.x, sk = 0;
    if constexpr (EPI == 2) { sk = bid & 1; bid >>= 1; }
    const int chunks_c = (N >> 8) / CC;
    const int xc = bid & 7;
    const int ii = bid >> 3;
    const int bm = (xc / chunks_c) * CR + ii / CC;
    const int bn = (xc % chunks_c) * CC + ii % CC;

    const size_t koff = (size_t)sk * nk * 64;
    const bf16* Abase = A + (size_t)bm * 256 * lda + koff;
    const bf16* Bbase = Bt + (size_t)bn * 256 * lda + koff;

    const unsigned aswz = (unsigned)(((lrow >> 1) & 3) << 4);
    const unsigned aoff0 = (unsigned)((wr * 128 + lrow) * 64 + lk2) ^ aswz;
    const unsigned boff0 = (unsigned)((wc * 64 + lrow) * 64 + lk2) ^ aswz;

    f32x4 acc[8][4] = {};

    // q: 0=Ak0, 1=Ak1, 2=Bk0, 3=Bk1 ; region = q*16KB in buffer (kt&1)
    auto STAGEQ = [&](int kt, int q) {
        const bf16* Pb = (q < 2) ? Abase : Bbase;
        const size_t kq = (size_t)kt * 64 + (size_t)(q & 1) * 32;
        char* reg = lds + (kt & 1) * 65536 + q * 16384;
        #pragma unroll
        for (int i2 = 0; i2 < 2; ++i2) {
            const int lin = i2 * 512 + t;
            const int row = lin >> 2;
            const int g = (lin & 3) ^ ((lin >> 3) & 3);
            gload16(Pb + (size_t)row * lda + kq + g * 8,
                    reg + (i2 * 512 + (t & 448)) * 16);
        }
    };

    auto PH_SYNC = [&]() {
        SB();
        __builtin_amdgcn_s_barrier();
        asm volatile("s_waitcnt lgkmcnt(0)");
        SB();
    };

    auto TILE64 = [&](int kt, bool dostage) {
        const char* bp = lds + (kt & 1) * 65536;
        bf16x8 av[4], bv[4], aw[4], av2[4], bv2[4], aw2[4];
        // ---------------- phase 1: k0, rows m0-3 ----------------
        #pragma unroll
        for (int m = 0; m < 4; ++m) av[m] = *(const bf16x8*)(bp + aoff0 + m * 1024);
        #pragma unroll
        for (int n = 0; n < 4; ++n) bv[n] = *(const bf16x8*)(bp + 32768 + boff0 + n * 1024);
        if (dostage) STAGEQ(kt + 1, 0);
        PH_SYNC();
        __builtin_amdgcn_s_setprio(1);
        #pragma unroll
        for (int m = 0; m < 4; ++m)
            #pragma unroll
            for (int n = 0; n < 4; ++n)
                acc[m][n] = __builtin_amdgcn_mfma_f32_16x16x32_bf16(av[m], bv[n], acc[m][n], 0, 0, 0);
        __builtin_amdgcn_s_setprio(0);
        // ---------------- phase 2: k0, rows m4-7 ----------------
        #pragma unroll
        for (int m = 0; m < 4; ++m) aw[m] = *(const bf16x8*)(bp + aoff0 + (m + 4) * 1024);
        if (dostage) { STAGEQ(kt + 1, 2); SB(); vmw<4>(); }
        else         { SB(); vmw<0>(); }
        PH_SYNC();
        __builtin_amdgcn_s_setprio(1);
        #pragma unroll
        for (int m = 0; m < 4; ++m)
            #pragma unroll
            for (int n = 0; n < 4; ++n)
                acc[m + 4][n] = __builtin_amdgcn_mfma_f32_16x16x32_bf16(aw[m], bv[n], acc[m + 4][n], 0, 0, 0);
        __builtin_amdgcn_s_setprio(0);
        // ---------------- phase 3: k1, rows m0-3 ----------------
        #pragma unroll
        for (int m = 0; m < 4; ++m) av2[m] = *(const bf16x8*)(bp + 16384 + aoff0 + m * 1024);
        #pragma unroll
        for (int n = 0; n < 4; ++n) bv2[n] = *(const bf16x8*)(bp + 49152 + boff0 + n * 1024);
        if (dostage) STAGEQ(kt + 1, 1);
        PH_SYNC();
        __builtin_amdgcn_s_setprio(1);
        #pragma unroll
        for (int m = 0; m < 4; ++m)
            #pragma unroll
            for (int n = 0; n < 4; ++n)
                acc[m][n] = __builtin_amdgcn_mfma_f32_16x16x32_bf16(av2[m], bv2[n], acc[m][n], 0, 0, 0);
        __builtin_amdgcn_s_setprio(0);
        // ---------------- phase 4: k1, rows m4-7 ----------------
        #pragma unroll
        for (int m = 0; m < 4; ++m) aw2[m] = *(const bf16x8*)(bp + 16384 + aoff0 + (m + 4) * 1024);
        if (dostage) { STAGEQ(kt + 1, 3); SB(); vmw<4>(); }
        PH_SYNC();
        __builtin_amdgcn_s_setprio(1);
        #pragma unroll
        for (int m = 0; m < 4; ++m)
            #pragma unroll
            for (int n = 0; n < 4; ++n)
                acc[m + 4][n] = __builtin_amdgcn_mfma_f32_16x16x32_bf16(aw2[m], bv2[n], acc[m + 4][n], 0, 0, 0);
        __builtin_amdgcn_s_setprio(0);
    };

    // prologue: all 4 quarters of tile 0, oldest = {Ak0, Bk0}
    STAGEQ(0, 0); STAGEQ(0, 2); STAGEQ(0, 1); STAGEQ(0, 3);
    SB(); vmw<4>();
    __builtin_amdgcn_s_barrier();
    SB();

    for (int kt = 0; kt < nk - 1; ++kt) TILE64(kt, true);
    TILE64(nk - 1, false);

    const int jrow = (lane >> 4) << 2;
    if constexpr (EPI == 1) {
        // all waves' phase-4 ds_reads completed before their own lgkmcnt(0);
        // barrier certifies that before we overwrite LDS with epilogue data.
        SB();
        __builtin_amdgcn_s_barrier();
        SB();
        float* xVl = (float*)lds;                 // 256 x 8
        float* Pl  = (float*)(lds + 8192);        // 8 x 256
        for (int idx = t; idx < 2048; idx += 512)
            xVl[idx] = e0[((size_t)bm * 256 + (idx >> 3)) * 8 + (idx & 7)];
        for (int idx = t; idx < 2048; idx += 512)
            Pl[idx] = e1[(size_t)(idx >> 8) * N + (size_t)bn * 256 + (idx & 255)];
        asm volatile("s_waitcnt lgkmcnt(0)");
        SB();
        __builtin_amdgcn_s_barrier();
        SB();
        bf16* outp = (bf16*)Cout;
        #pragma unroll
        for (int m = 0; m < 8; ++m)
            #pragma unroll
            for (int n = 0; n < 4; ++n)
                #pragma unroll
                for (int j = 0; j < 4; ++j) {
                    const int rl = wr * 128 + m * 16 + jrow + j;
                    const int cl = wc * 64 + n * 16 + lrow;
                    float v = acc[m][n][j];
                    float corr = 0.f;
                    #pragma unroll
                    for (int r = 0; r < 8; ++r)
                        corr = fmaf(xVl[rl * 8 + r], Pl[r * 256 + cl], corr);
                    v = fmaf(-2.f, corr, v);
                    v = 0.5f * v * (1.f + erff(v * 0.70710678118654752440f));
                    outp[((size_t)bm * 256 + rl) * N + bn * 256 + cl] = (bf16)v;
                }
    } else {
        float* outp = sk ? const_cast<float*>(e1) : (float*)Cout;
        #pragma unroll
        for (int m = 0; m < 8; ++m)
            #pragma unroll
            for (int n = 0; n < 4; ++n)
                #pragma unroll
                for (int j = 0; j < 4; ++j) {
                    const int rl = wr * 128 + m * 16 + jrow + j;
                    const int cl = wc * 64 + n * 16 + lrow;
                    outp[((size_t)bm * 256 + rl) * N + bn * 256 + cl] = acc[m][n][j];
                }
    }
}

extern "C" void kernel_launch(void* const* d_in, const int* in_sizes, int n_in,
                              void* d_out, int out_size, void* d_ws, size_t ws_size,
                              hipStream_t stream) {
    const float* x     = (const float*)d_in[0];
    const float* hra_u = (const float*)d_in[1];
    const float* Wr    = (const float*)d_in[2];
    const float* Wo    = (const float*)d_in[3];
    const float* bias  = (const float*)d_in[4];
    float* out = (float*)d_out;
    char* ws = (char*)d_ws;

    float* Vt  = (float*)(ws + 0);          //  64 KB : 8 x 2048
    float* P   = (float*)(ws + 65536);      // 256 KB : 8 x 8192
    float* xV  = (float*)(ws + 327680);     // 128 KB : 4096 x 8
    bf16*  xb  = (bf16*)(ws + 458752);      //  16 MB : 4096 x 2048
    bf16*  WrT = (bf16*)(ws + 17235968);    //  32 MB : 8192 x 2048
    bf16*  WoT = (bf16*)(ws + 50790400);    //  32 MB : 2048 x 8192
    bf16*  hb  = (bf16*)(ws + 84344832);    //  64 MB : 4096 x 8192
    // split-K partial for sk=1: 32 MB over xb+WrT head (both dead after GEMM1)
    float* p1  = (float*)(ws + 458752);

    gs_kernel<<<dim3(1), dim3(64), 0, stream>>>(hra_u, Vt);
    p_kernel<<<dim3(DHID / 32), dim3(256), 0, stream>>>(Wr, Vt, P);
    xv_kernel<<<dim3(NROWS / 4), dim3(256), 0, stream>>>(x, Vt, xV, xb);
    tconv_kernel<<<dim3(DHID / 64, DIN / 64), dim3(256), 0, stream>>>(Wr, WrT, DIN, DHID);
    tconv_kernel<<<dim3(DOUT / 64, DHID / 64), dim3(256), 0, stream>>>(Wo, WoT, DHID, DOUT);

    // GEMM1: 4096x8192 k=2048 (nk=32), 512 blocks (16x32 tiles), chunk 8x8
    gemm4p<8, 8, 1><<<dim3(512), dim3(512), 0, stream>>>(
        xb, WrT, DHID, DIN / 64, DIN, xV, P, (void*)hb);
    // GEMM2: 4096x2048, split-K=2 (nk=64 each), 256 blocks, chunk 4x4
    gemm4p<4, 4, 2><<<dim3(256), dim3(512), 0, stream>>>(
        hb, WoT, DOUT, DHID / 128, DHID, nullptr, p1, (void*)out);
    redk<<<dim3((NROWS * DOUT) / 1024), dim3(256), 0, stream>>>(out, p1, bias);
}